// Round 5
// baseline (714.119 us; speedup 1.0000x reference)
//
#include <hip/hip_runtime.h>
#include <hip/hip_bf16.h>
#include <cstdio>

// ---------------------------------------------------------------------------
// DinomalyBlock forward: B=8, N=4096, C=768, H=12, D=64, BN=384
// ---------------------------------------------------------------------------

typedef __attribute__((ext_vector_type(8))) short short8;
typedef __attribute__((ext_vector_type(4))) float floatx4;

__device__ __forceinline__ float bf2f(unsigned short u) {
    return __uint_as_float(((unsigned int)u) << 16);
}
__device__ __forceinline__ unsigned short f2bf(float f) {
    __hip_bfloat16 h = __float2bfloat16(f);
    return *reinterpret_cast<unsigned short*>(&h);
}

// async global->LDS, 16B/lane; LDS dest = wave-uniform base + lane*16
__device__ __forceinline__ void async_copy16(const unsigned short* g, unsigned short* l) {
    __builtin_amdgcn_global_load_lds(
        (const __attribute__((address_space(1))) unsigned int*)g,
        (__attribute__((address_space(3))) unsigned int*)l, 16, 0, 0);
}

__device__ __forceinline__ floatx4 MFMA16(short8 a, short8 b, floatx4 c) {
    return __builtin_amdgcn_mfma_f32_16x16x32_bf16(a, b, c, 0, 0, 0);
}

// ---------------- all weight transposes in one launch ----------------------
// W: [K][Nc] fp32 -> Wt: [Nc][K] bf16, 32x32 tiles
__global__ __launch_bounds__(256) void transpose_all(
    const float* __restrict__ wq, const float* __restrict__ wp,
    const float* __restrict__ wd, const float* __restrict__ wu,
    unsigned short* __restrict__ tq, unsigned short* __restrict__ tp,
    unsigned short* __restrict__ td, unsigned short* __restrict__ tu)
{
    int blk = blockIdx.x;
    const float* w; unsigned short* o; int K, Nc, tx32;
    if (blk < 1728)      { w = wq; o = tq; K = 768; Nc = 2304; tx32 = 24; }
    else if (blk < 2304) { w = wp; o = tp; K = 768; Nc = 768;  tx32 = 24; blk -= 1728; }
    else if (blk < 2592) { w = wd; o = td; K = 768; Nc = 384;  tx32 = 24; blk -= 2304; }
    else                 { w = wu; o = tu; K = 384; Nc = 768;  tx32 = 12; blk -= 2592; }
    int kb = (blk % tx32) * 32, nb = (blk / tx32) * 32;
    __shared__ float tile[32][33];
    int tx = threadIdx.x & 31, ty = threadIdx.x >> 5;   // 32x8
    #pragma unroll
    for (int i = 0; i < 32; i += 8)
        tile[ty + i][tx] = w[(size_t)(kb + ty + i) * Nc + nb + tx];
    __syncthreads();
    #pragma unroll
    for (int i = 0; i < 32; i += 8)
        o[(size_t)(nb + ty + i) * K + kb + tx] = f2bf(tile[tx][ty + i]);
}

// ---------------- LayerNorm over C=768, 384 threads ------------------------
template<bool OBF16>
__global__ __launch_bounds__(384) void ln_kernel(
    const float* __restrict__ in, const float* __restrict__ gw,
    const float* __restrict__ bw, void* __restrict__ outp)
{
    int row = blockIdx.x;
    int t = threadIdx.x;
    float2 xv = ((const float2*)(in + (size_t)row * 768))[t];
    float s = xv.x + xv.y;
    float ss = xv.x * xv.x + xv.y * xv.y;
    #pragma unroll
    for (int o = 32; o > 0; o >>= 1) {
        s += __shfl_down(s, o);
        ss += __shfl_down(ss, o);
    }
    __shared__ float red[14];
    int wave = t >> 6, lane = t & 63;
    if (lane == 0) { red[wave] = s; red[6 + wave] = ss; }
    __syncthreads();
    if (t == 0) {
        float S = 0.f, SS = 0.f;
        #pragma unroll
        for (int i = 0; i < 6; i++) { S += red[i]; SS += red[6 + i]; }
        float mu = S * (1.0f / 768.0f);
        float var = SS * (1.0f / 768.0f) - mu * mu;
        red[12] = mu;
        red[13] = rsqrtf(var + 1e-5f);
    }
    __syncthreads();
    float mu = red[12], rstd = red[13];
    float2 g = ((const float2*)gw)[t];
    float2 b = ((const float2*)bw)[t];
    float y0 = (xv.x - mu) * rstd * g.x + b.x;
    float y1 = (xv.y - mu) * rstd * g.y + b.y;
    if (OBF16) {
        unsigned int pk = (unsigned int)f2bf(y0) | ((unsigned int)f2bf(y1) << 16);
        ((unsigned int*)outp)[(size_t)row * 384 + t] = pk;
    } else {
        ((float2*)outp)[(size_t)row * 384 + t] = make_float2(y0, y1);
    }
}

// ---------------- fused residual add + LayerNorm ---------------------------
// s = bf16(y) + res ; out = LN(s)
template<bool RES_F32, bool OUT_F32>
__global__ __launch_bounds__(384) void add_ln_kernel(
    const unsigned short* __restrict__ y, const void* __restrict__ resv,
    const float* __restrict__ gw, const float* __restrict__ bw,
    void* __restrict__ outp)
{
    int row = blockIdx.x;
    int t = threadIdx.x;
    unsigned int yp = ((const unsigned int*)(y + (size_t)row * 768))[t];
    float a0 = bf2f((unsigned short)(yp & 0xffff));
    float a1 = bf2f((unsigned short)(yp >> 16));
    float r0, r1;
    if (RES_F32) {
        float2 rv = ((const float2*)((const float*)resv + (size_t)row * 768))[t];
        r0 = rv.x; r1 = rv.y;
    } else {
        unsigned int rp = ((const unsigned int*)((const unsigned short*)resv + (size_t)row * 768))[t];
        r0 = bf2f((unsigned short)(rp & 0xffff));
        r1 = bf2f((unsigned short)(rp >> 16));
    }
    float v0 = a0 + r0, v1 = a1 + r1;
    float s = v0 + v1;
    float ss = v0 * v0 + v1 * v1;
    #pragma unroll
    for (int o = 32; o > 0; o >>= 1) {
        s += __shfl_down(s, o);
        ss += __shfl_down(ss, o);
    }
    __shared__ float red[14];
    int wave = t >> 6, lane = t & 63;
    if (lane == 0) { red[wave] = s; red[6 + wave] = ss; }
    __syncthreads();
    if (t == 0) {
        float S = 0.f, SS = 0.f;
        #pragma unroll
        for (int i = 0; i < 6; i++) { S += red[i]; SS += red[6 + i]; }
        float mu = S * (1.0f / 768.0f);
        float var = SS * (1.0f / 768.0f) - mu * mu;
        red[12] = mu;
        red[13] = rsqrtf(var + 1e-5f);
    }
    __syncthreads();
    float mu = red[12], rstd = red[13];
    float2 g = ((const float2*)gw)[t];
    float2 b = ((const float2*)bw)[t];
    float y0 = (v0 - mu) * rstd * g.x + b.x;
    float y1 = (v1 - mu) * rstd * g.y + b.y;
    if (OUT_F32) {
        ((float2*)outp)[(size_t)row * 384 + t] = make_float2(y0, y1);
    } else {
        unsigned int pk = (unsigned int)f2bf(y0) | ((unsigned int)f2bf(y1) << 16);
        ((unsigned int*)outp)[(size_t)row * 384 + t] = pk;
    }
}

// ---------------- MFMA GEMM: out = A[M,K](bf16) @ Wt[Nc,K]^T + bias --------
// BK=64, XOR-swizzled LDS, 128x128 tile, 4 blocks/CU (proven structure).
// XCD-chunked supertile remap for L2 locality (banked: qkv FETCH 269->89 MB).
// MODE 0: elu+1 on cols<1536 (qkv) | 1: plain | 2: exact GELU
template<int MODE>
__global__ __launch_bounds__(256, 4) void gemm_kernel(
    const unsigned short* __restrict__ A,
    const unsigned short* __restrict__ Wt,
    const float* __restrict__ bias,
    unsigned short* __restrict__ outp,
    int M, int K, int Nc)
{
    __shared__ __align__(16) unsigned short As[128][64];
    __shared__ __align__(16) unsigned short Bs[128][64];

    const int gx = gridDim.x;
    const int gy = gridDim.y;
    int rb, cb;
    {   // XCD-chunked supertile remap (gy % 8 == 0 for all our launches)
        const int lid = blockIdx.y * gx + blockIdx.x;
        const int xcd = lid & 7;
        const int o   = lid >> 3;
        const int pry = gy >> 3;                       // row-panels per XCD
        const int cpg = (gx >= 12) ? (gx >> 1) : gx;   // cols per group
        const int per = pry * cpg;
        const int grp = o / per;
        const int o2  = o - grp * per;
        rb = xcd * pry + o2 / cpg;
        cb = grp * cpg + o2 % cpg;
    }
    const int row0 = rb * 128;
    const int col0 = cb * 128;

    const int t = threadIdx.x;
    const int lane = t & 63;
    const int wave = t >> 6;
    const int wm = (wave >> 1) * 64;
    const int wn = (wave & 1) * 64;
    const int frow = lane & 15;
    const int quad = lane >> 4;
    const int lrow = lane >> 3;                 // 0..7 within staging group
    const int lchunk = (lane & 7) ^ lrow;       // logical chunk this lane fetches

    floatx4 acc[4][4];
    #pragma unroll
    for (int i = 0; i < 4; i++)
        #pragma unroll
        for (int j = 0; j < 4; j++)
            acc[i][j] = (floatx4){0.f, 0.f, 0.f, 0.f};

    for (int k0 = 0; k0 < K; k0 += 64) {
        __syncthreads();   // previous iter's frag reads done
        #pragma unroll
        for (int q = 0; q < 4; q++) {
            int r = wave * 32 + q * 8 + lrow;
            async_copy16(A  + (size_t)(row0 + r) * K + k0 + lchunk * 8, &As[wave * 32 + q * 8][0]);
            async_copy16(Wt + (size_t)(col0 + r) * K + k0 + lchunk * 8, &Bs[wave * 32 + q * 8][0]);
        }
        __syncthreads();   // drains vmcnt
        #pragma unroll
        for (int ks = 0; ks < 2; ks++) {
            const int pc = ((ks * 4 + quad) ^ (frow & 7)) * 8;
            short8 af[4], bf4[4];
            #pragma unroll
            for (int i = 0; i < 4; i++) af[i] = *(const short8*)&As[wm + i * 16 + frow][pc];
            #pragma unroll
            for (int j = 0; j < 4; j++) bf4[j] = *(const short8*)&Bs[wn + j * 16 + frow][pc];
            #pragma unroll
            for (int i = 0; i < 4; i++)
                #pragma unroll
                for (int j = 0; j < 4; j++)
                    acc[i][j] = MFMA16(af[i], bf4[j], acc[i][j]);
        }
    }

    #pragma unroll
    for (int i = 0; i < 4; i++) {
        #pragma unroll
        for (int j = 0; j < 4; j++) {
            int col = col0 + wn + j * 16 + frow;
            float bcol = bias[col];
            #pragma unroll
            for (int rr = 0; rr < 4; rr++) {
                int row = row0 + wm + i * 16 + quad * 4 + rr;
                float v = acc[i][j][rr] + bcol;
                if (MODE == 0) {
                    if (col < 1536) v = (v > 0.f) ? (v + 1.f) : expf(v);
                } else if (MODE == 2) {
                    v = 0.5f * v * (1.0f + erff(v * 0.70710678118654752f));
                }
                outp[(size_t)row * Nc + col] = f2bf(v);
            }
        }
    }
}

// ---------------- 256x256 deep-pipelined MFMA GEMM (attempt 3) -------------
// BM=BN=256, BK=64, 512 thr (8 waves 2Mx4N). LDS: As/Bs[2][256][64] bf16
// (128B rows, zero-conflict XOR pattern, correctness-proven in r2) = 128 KiB.
// Pipeline fix vs r2: ALL 8 loads of tile u+1 issue at ph0 of iter u (slot
// sl^1 free since iter u-1's trailing barrier); single vmcnt(0) at end-ph3
// gives every load a ~4-phase (~1200 cyc) issue->wait distance > HBM latency.
template<int MODE>
__global__ __launch_bounds__(512, 2) void gemm256(
    const unsigned short* __restrict__ A,
    const unsigned short* __restrict__ Wt,
    const float* __restrict__ bias,
    unsigned short* __restrict__ outp,
    int M, int K, int Nc)
{
    __shared__ __align__(16) unsigned short As[2][256][64];
    __shared__ __align__(16) unsigned short Bs[2][256][64];

    // bijective XCD swizzle (all launches have nwg % 8 == 0)
    const int gx = gridDim.x;
    const int nwg = gx * gridDim.y;
    const int lid = blockIdx.y * gx + blockIdx.x;
    const int cpx = nwg >> 3;
    const int swz = (lid & 7) * cpx + (lid >> 3);
    const int row0 = (swz / gx) * 256;
    const int col0 = (swz % gx) * 256;

    const int t = threadIdx.x;
    const int lane = t & 63;
    const int wave = t >> 6;          // 0..7
    const int wm = wave >> 2;         // 0..1 (M wave)
    const int wn = wave & 3;          // 0..3 (N wave)
    const int frow = lane & 15;
    const int quad = lane >> 4;

    // staging: per wave-instr 64 lanes x 16B = 8 rows of 128B; global source
    // pre-swizzled (chunk (lane&7)^(lane>>3)) so LDS dest stays linear.
    const int lrow = lane >> 3;            // 0..7
    const int lch  = (lane & 7) ^ lrow;    // global 16B chunk this lane fetches
    const unsigned short* Ag = A  + (size_t)(row0 + wave * 8 + lrow) * K + lch * 8;
    const unsigned short* Bg = Wt + (size_t)(col0 + wave * 8 + lrow) * K + lch * 8;

    const int nt = K >> 6;

    floatx4 acc[8][4];
    #pragma unroll
    for (int i = 0; i < 8; i++)
        #pragma unroll
        for (int j = 0; j < 4; j++)
            acc[i][j] = (floatx4){0.f, 0.f, 0.f, 0.f};
    short8 af[4], bf[4];

    // stage half h of tile -> slot: 2 strips (s=0: rows h*64.., s=1: 128+h*64..)
    auto stageA = [&](int slot, int h, int tile) {
        const unsigned short* g = Ag + (size_t)tile * 64;
        async_copy16(g + (size_t)(h * 64) * K,        &As[slot][h * 64 + wave * 8][0]);
        async_copy16(g + (size_t)(128 + h * 64) * K,  &As[slot][128 + h * 64 + wave * 8][0]);
    };
    auto stageB = [&](int slot, int h, int tile) {
        const unsigned short* g = Bg + (size_t)tile * 64;
        async_copy16(g + (size_t)(h * 64) * K,        &Bs[slot][h * 64 + wave * 8][0]);
        async_copy16(g + (size_t)(128 + h * 64) * K,  &Bs[slot][128 + h * 64 + wave * 8][0]);
    };
    auto ldA = [&](int slot, int ks, int ih) {
        const int pc = ((ks * 4 + quad) ^ (frow & 7)) * 8;
        #pragma unroll
        for (int ii = 0; ii < 4; ii++)
            af[ii] = *(const short8*)&As[slot][wm * 128 + ih * 64 + ii * 16 + frow][pc];
    };
    auto ldB = [&](int slot, int ks) {
        const int pc = ((ks * 4 + quad) ^ (frow & 7)) * 8;
        #pragma unroll
        for (int j = 0; j < 4; j++)
            bf[j] = *(const short8*)&Bs[slot][wn * 64 + j * 16 + frow][pc];
    };
    auto mm = [&](int ih) {
        __builtin_amdgcn_s_setprio(1);
        #pragma unroll
        for (int ii = 0; ii < 4; ii++)
            #pragma unroll
            for (int j = 0; j < 4; j++)
                acc[ih * 4 + ii][j] = MFMA16(af[ii], bf[j], acc[ih * 4 + ii][j]);
        __builtin_amdgcn_s_setprio(0);
    };

    // prologue: tile0 fully into slot 0 (8 loads/wave), drain, barrier
    stageA(0, 0, 0); stageB(0, 0, 0);
    stageA(0, 1, 0); stageB(0, 1, 0);
    asm volatile("s_waitcnt vmcnt(0)" ::: "memory");
    __builtin_amdgcn_s_barrier();

    for (int u = 0; u < nt; u++) {
        const int sl = u & 1;
        // ---- ph0: ks0, ihalf0; stage ALL of tile u+1 (8 loads, 4-phase depth)
        ldB(sl, 0); ldA(sl, 0, 0);
        if (u + 1 < nt) {
            stageA(sl ^ 1, 0, u + 1); stageB(sl ^ 1, 0, u + 1);
            stageA(sl ^ 1, 1, u + 1); stageB(sl ^ 1, 1, u + 1);
        }
        __builtin_amdgcn_s_barrier();
        asm volatile("s_waitcnt lgkmcnt(0)" ::: "memory");
        mm(0);
        __builtin_amdgcn_s_barrier();
        // ---- ph1: ks0, ihalf1 (bf reused)
        ldA(sl, 0, 1);
        __builtin_amdgcn_s_barrier();
        asm volatile("s_waitcnt lgkmcnt(0)" ::: "memory");
        mm(1);
        __builtin_amdgcn_s_barrier();
        // ---- ph2: ks1, ihalf0
        ldB(sl, 1); ldA(sl, 1, 0);
        __builtin_amdgcn_s_barrier();
        asm volatile("s_waitcnt lgkmcnt(0)" ::: "memory");
        mm(0);
        __builtin_amdgcn_s_barrier();
        // ---- ph3: ks1, ihalf1; tile u+1 must land (issued 4 phases ago)
        ldA(sl, 1, 1);
        __builtin_amdgcn_s_barrier();
        asm volatile("s_waitcnt lgkmcnt(0)" ::: "memory");
        mm(1);
        asm volatile("s_waitcnt vmcnt(0)" ::: "memory");
        __builtin_amdgcn_s_barrier();
    }

    #pragma unroll
    for (int i = 0; i < 8; i++) {
        #pragma unroll
        for (int j = 0; j < 4; j++) {
            int col = col0 + wn * 64 + j * 16 + frow;
            float bcol = bias[col];
            #pragma unroll
            for (int rr = 0; rr < 4; rr++) {
                int row = row0 + wm * 128 + i * 16 + quad * 4 + rr;
                float v = acc[i][j][rr] + bcol;
                if (MODE == 0) {
                    if (col < 1536) v = (v > 0.f) ? (v + 1.f) : expf(v);
                } else if (MODE == 2) {
                    v = 0.5f * v * (1.0f + erff(v * 0.70710678118654752f));
                }
                outp[(size_t)row * Nc + col] = f2bf(v);
            }
        }
    }
}

// ---------------- linear attention: kv accumulation ------------------------
// grid = B*H*8 (512 rows each); kvbuf[bh] 4160 fp32: [e*64+d]=kvT, [4096+d]=ksum
// Single-buffer LDS (35 KB) -> 4 blocks/CU; next chunk register-prefetched
// so HBM latency hides under compute. Accumulation order unchanged.
__global__ __launch_bounds__(256, 4) void kv_accum(
    const unsigned short* __restrict__ qkv, float* __restrict__ kvbuf)
{
    int blk = blockIdx.x;
    int chunk = blk & 7;
    int bh = blk >> 3;
    int b = bh / 12, h = bh % 12;
    int n0 = chunk * 512;
    int t = threadIdx.x;
    int d = t & 63, g = t >> 6;
    __shared__ float kl[32][68];
    __shared__ float vl[32][68];
    float kv[16];
    #pragma unroll
    for (int j = 0; j < 16; j++) kv[j] = 0.f;
    float ks = 0.f;

    int sr = t >> 3;            // staging row 0..31
    int c16 = (t & 7) * 16;     // 0..112
    bool isk = c16 < 64;
    int cc = isk ? c16 : c16 - 64;
    const unsigned short* gbase =
        qkv + (size_t)(b * 4096 + n0 + sr) * 2304 + (isk ? 768 : 1536) + h * 64 + cc;
    uint4 r0, r1;
    auto loadg = [&](int nb) {
        const uint4* s = (const uint4*)(gbase + (size_t)nb * 2304);
        r0 = s[0]; r1 = s[1];
    };
    auto storel = [&]() {
        float* dst = isk ? &kl[sr][cc] : &vl[sr][cc];
        const unsigned short* u0 = (const unsigned short*)&r0;
        const unsigned short* u1 = (const unsigned short*)&r1;
        #pragma unroll
        for (int i = 0; i < 8; i++) dst[i] = bf2f(u0[i]);
        #pragma unroll
        for (int i = 0; i < 8; i++) dst[8 + i] = bf2f(u1[i]);
    };

    loadg(0);
    for (int c = 0; c < 16; c++) {
        storel();                       // chunk c regs -> LDS
        __syncthreads();                // writes visible
        if (c < 15) loadg((c + 1) * 32);   // prefetch next (hides under compute)
        #pragma unroll 8
        for (int r2 = 0; r2 < 32; r2++) {
            float kd = kl[r2][d];
            ks += kd;
            const float4* vv = (const float4*)&vl[r2][g * 16];
            float4 a0 = vv[0], a1 = vv[1], a2 = vv[2], a3 = vv[3];
            kv[0]  += kd * a0.x; kv[1]  += kd * a0.y; kv[2]  += kd * a0.z; kv[3]  += kd * a0.w;
            kv[4]  += kd * a1.x; kv[5]  += kd * a1.y; kv[6]  += kd * a1.z; kv[7]  += kd * a1.w;
            kv[8]  += kd * a2.x; kv[9]  += kd * a2.y; kv[10] += kd * a2.z; kv[11] += kd * a2.w;
            kv[12] += kd * a3.x; kv[13] += kd * a3.y; kv[14] += kd * a3.z; kv[15] += kd * a3.w;
        }
        __syncthreads();                // all reads done before next storel
    }
    float* dstg = kvbuf + (size_t)bh * 4160;
    #pragma unroll
    for (int j = 0; j < 16; j++)
        atomicAdd(&dstg[(g * 16 + j) * 64 + d], kv[j]);   // transposed: [e][d]
    if (g == 0) atomicAdd(&dstg[4096 + d], ks);
}

// ---------------- linear attention: apply via MFMA -------------------------
__global__ __launch_bounds__(256) void attn_apply(
    const unsigned short* __restrict__ qkv, const float* __restrict__ kvbuf,
    unsigned short* __restrict__ attnC)
{
    int blk = blockIdx.x;
    int nchunk = blk & 31;
    int bh = blk >> 5;
    int b = bh / 12, h = bh % 12;
    int n0 = nchunk * 128;
    int t = threadIdx.x;
    int lane = t & 63, wave = t >> 6;
    __shared__ __align__(16) unsigned short ql[128][72];
    __shared__ __align__(16) unsigned short Bs[80][72];

    {   // stage kvT (fp32->bf16) rows 0..63; ksum row 64; zeros 65..79
        const float* kvg = kvbuf + (size_t)bh * 4160;
        int e = t >> 2, d0 = (t & 3) * 16;
        const float4* src4 = (const float4*)(kvg + e * 64 + d0);
        #pragma unroll
        for (int i = 0; i < 4; i++) {
            float4 v = src4[i];
            unsigned long long pk = (unsigned long long)f2bf(v.x)
                | ((unsigned long long)f2bf(v.y) << 16)
                | ((unsigned long long)f2bf(v.z) << 32)
                | ((unsigned long long)f2bf(v.w) << 48);
            *(unsigned long long*)&Bs[e][d0 + i * 4] = pk;
        }
        if (t < 64) {
            Bs[64][t] = f2bf(kvg[4096 + t]);
            #pragma unroll
            for (int r = 65; r < 80; r++) Bs[r][t] = 0;
        }
    }
    {   // stage q rows (raw bf16 copy)
        int r = t >> 1, c0 = (t & 1) * 32;
        const uint4* src = (const uint4*)(qkv + (size_t)(b * 4096 + n0 + r) * 2304 + h * 64 + c0);
        uint4* dst = (uint4*)&ql[r][c0];
        #pragma unroll
        for (int i = 0; i < 4; i++) dst[i] = src[i];
    }
    __syncthreads();

    int frow = lane & 15, quad = lane >> 4;
    floatx4 acc[2][5];
    #pragma unroll
    for (int it = 0; it < 2; it++)
        #pragma unroll
        for (int jt = 0; jt < 5; jt++)
            acc[it][jt] = (floatx4){0.f, 0.f, 0.f, 0.f};

    #pragma unroll
    for (int ks = 0; ks < 2; ks++) {
        int fk = ks * 32 + quad * 8;
        short8 a0 = *(const short8*)&ql[wave * 32 + frow][fk];
        short8 a1 = *(const short8*)&ql[wave * 32 + 16 + frow][fk];
        #pragma unroll
        for (int jt = 0; jt < 5; jt++) {
            short8 bb = *(const short8*)&Bs[jt * 16 + frow][fk];
            acc[0][jt] = __builtin_amdgcn_mfma_f32_16x16x32_bf16(a0, bb, acc[0][jt], 0, 0, 0);
            acc[1][jt] = __builtin_amdgcn_mfma_f32_16x16x32_bf16(a1, bb, acc[1][jt], 0, 0, 0);
        }
    }

    #pragma unroll
    for (int it = 0; it < 2; it++) {
        #pragma unroll
        for (int rr = 0; rr < 4; rr++) {
            float nv = __shfl(acc[it][4][rr], (lane & 48));   // norm from col 0 of tile 4
            float inv = 1.0f / (nv + 1e-6f);
            int row = n0 + wave * 32 + it * 16 + quad * 4 + rr;
            size_t obase = (size_t)(b * 4096 + row) * 768 + h * 64;
            #pragma unroll
            for (int jt = 0; jt < 4; jt++)
                attnC[obase + jt * 16 + frow] = f2bf(acc[it][jt][rr] * inv);
        }
    }
}

// ---------------------------------------------------------------------------
extern "C" void kernel_launch(void* const* d_in, const int* in_sizes, int n_in,
                              void* d_out, int out_size, void* d_ws, size_t ws_size,
                              hipStream_t stream)
{
    const float* x      = (const float*)d_in[0];
    const float* w_qkv  = (const float*)d_in[1];
    const float* b_qkv  = (const float*)d_in[2];
    const float* w_proj = (const float*)d_in[3];
    const float* b_proj = (const float*)d_in[4];
    const float* g1     = (const float*)d_in[5];
    const float* be1    = (const float*)d_in[6];
    const float* g2     = (const float*)d_in[7];
    const float* be2    = (const float*)d_in[8];
    const float* w_down = (const float*)d_in[9];
    const float* b_down = (const float*)d_in[10];
    const float* w_up   = (const float*)d_in[11];
    const float* b_up   = (const float*)d_in[12];
    const float* g3     = (const float*)d_in[13];
    const float* be3    = (const float*)d_in[14];

    char* p = (char*)d_ws;
    auto take = [&](size_t b) { char* q = p; p += (b + 255) & ~(size_t)255; return q; };
    unsigned short* wtq  = (unsigned short*)take((size_t)2304 * 768 * 2);
    unsigned short* wtp  = (unsigned short*)take((size_t)768 * 768 * 2);
    unsigned short* wtd  = (unsigned short*)take((size_t)384 * 768 * 2);
    unsigned short* wtu  = (unsigned short*)take((size_t)768 * 384 * 2);
    unsigned short* bufA = (unsigned short*)take((size_t)32768 * 768 * 2);  // ln1 / attnC
    unsigned short* qkvb = (unsigned short*)take((size_t)32768 * 2304 * 2); // qkv; then r/projout/upout
    float*          kvb  = (float*)take((size_t)96 * 4160 * 4);
    unsigned short* hbuf = (unsigned short*)take((size_t)32768 * 384 * 2);
    // qkv dead after attn_apply; carve its 151 MB into three 50 MB bf16 buffers
    unsigned short* rbuf    = qkvb;
    unsigned short* projout = qkvb + (size_t)32768 * 768;
    unsigned short* upout   = qkvb + (size_t)2 * 32768 * 768;

    size_t needed = (size_t)(p - (char*)d_ws);
    if (needed > ws_size)
        fprintf(stderr, "WARNING: ws too small: need %zu have %zu\n", needed, ws_size);

    transpose_all<<<2880, 256, 0, stream>>>(w_qkv, w_proj, w_down, w_up, wtq, wtp, wtd, wtu);
    hipMemsetAsync(kvb, 0, (size_t)96 * 4160 * 4, stream);

    // ln1 = LN(x) (bf16)
    ln_kernel<true><<<32768, 384, 0, stream>>>(x, g1, be1, bufA);
    // qkv = ln1 @ Wqkv + b, elu+1 on q,k   (256^2 deep-pipelined, attempt 3)
    gemm256<0><<<dim3(9, 128), 512, 0, stream>>>(bufA, wtq, b_qkv, qkvb, 32768, 768, 2304);
    // attention
    kv_accum<<<768, 256, 0, stream>>>(qkvb, kvb);
    attn_apply<<<3072, 256, 0, stream>>>(qkvb, kvb, bufA);
    // projout = attn @ Wproj + b (bf16, no residual)  — banked 128^2 path
    gemm_kernel<1><<<dim3(6, 256), 256, 0, stream>>>(bufA, wtp, b_proj, projout, 32768, 768, 768);
    // r = LN(x + projout) (bf16)
    add_ln_kernel<true, false><<<32768, 384, 0, stream>>>(projout, x, g2, be2, rbuf);
    // h = gelu(r @ Wdown + b) (bf16)
    gemm_kernel<2><<<dim3(3, 256), 256, 0, stream>>>(rbuf, wtd, b_down, hbuf, 32768, 768, 384);
    // upout = h @ Wup + b (bf16)
    gemm_kernel<1><<<dim3(6, 256), 256, 0, stream>>>(hbuf, wtu, b_up, upout, 32768, 384, 768);
    // out = LN(r + upout) (fp32, d_out)
    add_ln_kernel<false, true><<<32768, 384, 0, stream>>>(upout, rbuf, g3, be3, (float*)d_out);
}

// Round 6
// 646.583 us; speedup vs baseline: 1.1045x; 1.1045x over previous
//
#include <hip/hip_runtime.h>
#include <hip/hip_bf16.h>
#include <cstdio>

// ---------------------------------------------------------------------------
// DinomalyBlock forward: B=8, N=4096, C=768, H=12, D=64, BN=384
// ---------------------------------------------------------------------------

typedef __attribute__((ext_vector_type(8))) short short8;
typedef __attribute__((ext_vector_type(4))) float floatx4;

__device__ __forceinline__ float bf2f(unsigned short u) {
    return __uint_as_float(((unsigned int)u) << 16);
}
__device__ __forceinline__ unsigned short f2bf(float f) {
    __hip_bfloat16 h = __float2bfloat16(f);
    return *reinterpret_cast<unsigned short*>(&h);
}

// async global->LDS, 16B/lane; LDS dest = wave-uniform base + lane*16
__device__ __forceinline__ void async_copy16(const unsigned short* g, unsigned short* l) {
    __builtin_amdgcn_global_load_lds(
        (const __attribute__((address_space(1))) unsigned int*)g,
        (__attribute__((address_space(3))) unsigned int*)l, 16, 0, 0);
}

__device__ __forceinline__ floatx4 MFMA16(short8 a, short8 b, floatx4 c) {
    return __builtin_amdgcn_mfma_f32_16x16x32_bf16(a, b, c, 0, 0, 0);
}

// ---------------- all weight transposes in one launch ----------------------
// W: [K][Nc] fp32 -> Wt: [Nc][K] bf16, 32x32 tiles
__global__ __launch_bounds__(256) void transpose_all(
    const float* __restrict__ wq, const float* __restrict__ wp,
    const float* __restrict__ wd, const float* __restrict__ wu,
    unsigned short* __restrict__ tq, unsigned short* __restrict__ tp,
    unsigned short* __restrict__ td, unsigned short* __restrict__ tu)
{
    int blk = blockIdx.x;
    const float* w; unsigned short* o; int K, Nc, tx32;
    if (blk < 1728)      { w = wq; o = tq; K = 768; Nc = 2304; tx32 = 24; }
    else if (blk < 2304) { w = wp; o = tp; K = 768; Nc = 768;  tx32 = 24; blk -= 1728; }
    else if (blk < 2592) { w = wd; o = td; K = 768; Nc = 384;  tx32 = 24; blk -= 2304; }
    else                 { w = wu; o = tu; K = 384; Nc = 768;  tx32 = 12; blk -= 2592; }
    int kb = (blk % tx32) * 32, nb = (blk / tx32) * 32;
    __shared__ float tile[32][33];
    int tx = threadIdx.x & 31, ty = threadIdx.x >> 5;   // 32x8
    #pragma unroll
    for (int i = 0; i < 32; i += 8)
        tile[ty + i][tx] = w[(size_t)(kb + ty + i) * Nc + nb + tx];
    __syncthreads();
    #pragma unroll
    for (int i = 0; i < 32; i += 8)
        o[(size_t)(nb + ty + i) * K + kb + tx] = f2bf(tile[tx][ty + i]);
}

// ---------------- LayerNorm over C=768 -------------------------------------
// 2 rows per 384-thread block; 192 threads/row, float4 (16B) loads.
template<bool OBF16>
__global__ __launch_bounds__(384) void ln_kernel(
    const float* __restrict__ in, const float* __restrict__ gw,
    const float* __restrict__ bw, void* __restrict__ outp)
{
    int t = threadIdx.x;
    int half = (t >= 192) ? 1 : 0;
    int tt = t - half * 192;             // 0..191 within row
    int row = blockIdx.x * 2 + half;
    float4 xv = ((const float4*)(in + (size_t)row * 768))[tt];
    float s = xv.x + xv.y + xv.z + xv.w;
    float ss = xv.x * xv.x + xv.y * xv.y + xv.z * xv.z + xv.w * xv.w;
    #pragma unroll
    for (int o = 32; o > 0; o >>= 1) {
        s += __shfl_down(s, o);
        ss += __shfl_down(ss, o);
    }
    __shared__ float red[16];
    int wave = t >> 6, lane = t & 63;    // waves 0-2 row0, 3-5 row1
    if (lane == 0) { red[wave] = s; red[8 + wave] = ss; }
    __syncthreads();
    if (tt == 0) {                        // t==0 and t==192
        int w0 = half * 3;
        float S = red[w0] + red[w0 + 1] + red[w0 + 2];
        float SS = red[8 + w0] + red[8 + w0 + 1] + red[8 + w0 + 2];
        float mu = S * (1.0f / 768.0f);
        float var = SS * (1.0f / 768.0f) - mu * mu;
        red[6 + half] = mu;
        red[14 + half] = rsqrtf(var + 1e-5f);
    }
    __syncthreads();
    float mu = red[6 + half], rstd = red[14 + half];
    float4 g = ((const float4*)gw)[tt];
    float4 b = ((const float4*)bw)[tt];
    float y0 = (xv.x - mu) * rstd * g.x + b.x;
    float y1 = (xv.y - mu) * rstd * g.y + b.y;
    float y2 = (xv.z - mu) * rstd * g.z + b.z;
    float y3 = (xv.w - mu) * rstd * g.w + b.w;
    if (OBF16) {
        uint2 pk;
        pk.x = (unsigned int)f2bf(y0) | ((unsigned int)f2bf(y1) << 16);
        pk.y = (unsigned int)f2bf(y2) | ((unsigned int)f2bf(y3) << 16);
        ((uint2*)outp)[(size_t)row * 192 + tt] = pk;
    } else {
        ((float4*)outp)[(size_t)row * 192 + tt] = make_float4(y0, y1, y2, y3);
    }
}

// ---------------- fused residual add + LayerNorm ---------------------------
// s = bf16(y) + res ; out = LN(s).  2 rows/block, 192 thr/row, wide loads.
template<bool RES_F32, bool OUT_F32>
__global__ __launch_bounds__(384) void add_ln_kernel(
    const unsigned short* __restrict__ y, const void* __restrict__ resv,
    const float* __restrict__ gw, const float* __restrict__ bw,
    void* __restrict__ outp)
{
    int t = threadIdx.x;
    int half = (t >= 192) ? 1 : 0;
    int tt = t - half * 192;
    int row = blockIdx.x * 2 + half;
    uint2 yp = ((const uint2*)(y + (size_t)row * 768))[tt];   // 4 bf16, 8B
    float a0 = bf2f((unsigned short)(yp.x & 0xffff));
    float a1 = bf2f((unsigned short)(yp.x >> 16));
    float a2 = bf2f((unsigned short)(yp.y & 0xffff));
    float a3 = bf2f((unsigned short)(yp.y >> 16));
    float r0, r1, r2, r3;
    if (RES_F32) {
        float4 rv = ((const float4*)((const float*)resv + (size_t)row * 768))[tt];
        r0 = rv.x; r1 = rv.y; r2 = rv.z; r3 = rv.w;
    } else {
        uint2 rp = ((const uint2*)((const unsigned short*)resv + (size_t)row * 768))[tt];
        r0 = bf2f((unsigned short)(rp.x & 0xffff));
        r1 = bf2f((unsigned short)(rp.x >> 16));
        r2 = bf2f((unsigned short)(rp.y & 0xffff));
        r3 = bf2f((unsigned short)(rp.y >> 16));
    }
    float v0 = a0 + r0, v1 = a1 + r1, v2 = a2 + r2, v3 = a3 + r3;
    float s = v0 + v1 + v2 + v3;
    float ss = v0 * v0 + v1 * v1 + v2 * v2 + v3 * v3;
    #pragma unroll
    for (int o = 32; o > 0; o >>= 1) {
        s += __shfl_down(s, o);
        ss += __shfl_down(ss, o);
    }
    __shared__ float red[16];
    int wave = t >> 6, lane = t & 63;
    if (lane == 0) { red[wave] = s; red[8 + wave] = ss; }
    __syncthreads();
    if (tt == 0) {
        int w0 = half * 3;
        float S = red[w0] + red[w0 + 1] + red[w0 + 2];
        float SS = red[8 + w0] + red[8 + w0 + 1] + red[8 + w0 + 2];
        float mu = S * (1.0f / 768.0f);
        float var = SS * (1.0f / 768.0f) - mu * mu;
        red[6 + half] = mu;
        red[14 + half] = rsqrtf(var + 1e-5f);
    }
    __syncthreads();
    float mu = red[6 + half], rstd = red[14 + half];
    float4 g = ((const float4*)gw)[tt];
    float4 b = ((const float4*)bw)[tt];
    float y0 = (v0 - mu) * rstd * g.x + b.x;
    float y1 = (v1 - mu) * rstd * g.y + b.y;
    float y2 = (v2 - mu) * rstd * g.z + b.z;
    float y3 = (v3 - mu) * rstd * g.w + b.w;
    if (OUT_F32) {
        ((float4*)outp)[(size_t)row * 192 + tt] = make_float4(y0, y1, y2, y3);
    } else {
        uint2 pk;
        pk.x = (unsigned int)f2bf(y0) | ((unsigned int)f2bf(y1) << 16);
        pk.y = (unsigned int)f2bf(y2) | ((unsigned int)f2bf(y3) << 16);
        ((uint2*)outp)[(size_t)row * 192 + tt] = pk;
    }
}

// ---------------- MFMA GEMM: out = A[M,K](bf16) @ Wt[Nc,K]^T + bias --------
// BK=64, XOR-swizzled LDS; grid = dim3(NCT, NRT): col-fastest dispatch so
// consecutive blocks share one A row-panel (round-0 proven mapping; the XCD
// supertile remap reduced FETCH 269->89 MB but SLOWED qkv 146->161 us:
// memory was not the limiter and the per-XCD set slightly overflowed L2).
// MODE 0: elu+1 on cols<1536 (qkv) | 1: plain | 2: exact GELU
template<int MODE>
__global__ __launch_bounds__(256, 4) void gemm_kernel(
    const unsigned short* __restrict__ A,
    const unsigned short* __restrict__ Wt,
    const float* __restrict__ bias,
    unsigned short* __restrict__ outp,
    int M, int K, int Nc)
{
    __shared__ __align__(16) unsigned short As[128][64];
    __shared__ __align__(16) unsigned short Bs[128][64];
    const int row0 = blockIdx.y * 128;   // slow dim
    const int col0 = blockIdx.x * 128;   // fast dim -> col-fastest dispatch
    const int t = threadIdx.x;
    const int lane = t & 63;
    const int wave = t >> 6;
    const int wm = (wave >> 1) * 64;
    const int wn = (wave & 1) * 64;
    const int frow = lane & 15;
    const int quad = lane >> 4;
    const int lrow = lane >> 3;                 // 0..7 within staging group
    const int lchunk = (lane & 7) ^ lrow;       // logical chunk this lane fetches

    floatx4 acc[4][4];
    #pragma unroll
    for (int i = 0; i < 4; i++)
        #pragma unroll
        for (int j = 0; j < 4; j++)
            acc[i][j] = (floatx4){0.f, 0.f, 0.f, 0.f};

    for (int k0 = 0; k0 < K; k0 += 64) {
        __syncthreads();   // previous iter's frag reads done
        #pragma unroll
        for (int q = 0; q < 4; q++) {
            int r = wave * 32 + q * 8 + lrow;
            async_copy16(A  + (size_t)(row0 + r) * K + k0 + lchunk * 8, &As[wave * 32 + q * 8][0]);
            async_copy16(Wt + (size_t)(col0 + r) * K + k0 + lchunk * 8, &Bs[wave * 32 + q * 8][0]);
        }
        __syncthreads();   // drains vmcnt
        #pragma unroll
        for (int ks = 0; ks < 2; ks++) {
            const int pc = ((ks * 4 + quad) ^ (frow & 7)) * 8;
            short8 af[4], bf4[4];
            #pragma unroll
            for (int i = 0; i < 4; i++) af[i] = *(const short8*)&As[wm + i * 16 + frow][pc];
            #pragma unroll
            for (int j = 0; j < 4; j++) bf4[j] = *(const short8*)&Bs[wn + j * 16 + frow][pc];
            #pragma unroll
            for (int i = 0; i < 4; i++)
                #pragma unroll
                for (int j = 0; j < 4; j++)
                    acc[i][j] = MFMA16(af[i], bf4[j], acc[i][j]);
        }
    }

    #pragma unroll
    for (int i = 0; i < 4; i++) {
        #pragma unroll
        for (int j = 0; j < 4; j++) {
            int col = col0 + wn + j * 16 + frow;
            float bcol = bias[col];
            #pragma unroll
            for (int rr = 0; rr < 4; rr++) {
                int row = row0 + wm + i * 16 + quad * 4 + rr;
                float v = acc[i][j][rr] + bcol;
                if (MODE == 0) {
                    if (col < 1536) v = (v > 0.f) ? (v + 1.f) : expf(v);
                } else if (MODE == 2) {
                    v = 0.5f * v * (1.0f + erff(v * 0.70710678118654752f));
                }
                outp[(size_t)row * Nc + col] = f2bf(v);
            }
        }
    }
}

// ---------------- linear attention: kv accumulation ------------------------
// grid = B*H*8 (512 rows each); kvbuf[bh] 4160 fp32: [e*64+d]=kvT, [4096+d]=ksum
// Single-buffer LDS (35 KB) -> 4 blocks/CU; next chunk register-prefetched
// so HBM latency hides under compute. Accumulation order unchanged.
__global__ __launch_bounds__(256, 4) void kv_accum(
    const unsigned short* __restrict__ qkv, float* __restrict__ kvbuf)
{
    int blk = blockIdx.x;
    int chunk = blk & 7;
    int bh = blk >> 3;
    int b = bh / 12, h = bh % 12;
    int n0 = chunk * 512;
    int t = threadIdx.x;
    int d = t & 63, g = t >> 6;
    __shared__ float kl[32][68];
    __shared__ float vl[32][68];
    float kv[16];
    #pragma unroll
    for (int j = 0; j < 16; j++) kv[j] = 0.f;
    float ks = 0.f;

    int sr = t >> 3;            // staging row 0..31
    int c16 = (t & 7) * 16;     // 0..112
    bool isk = c16 < 64;
    int cc = isk ? c16 : c16 - 64;
    const unsigned short* gbase =
        qkv + (size_t)(b * 4096 + n0 + sr) * 2304 + (isk ? 768 : 1536) + h * 64 + cc;
    uint4 r0, r1;
    auto loadg = [&](int nb) {
        const uint4* s = (const uint4*)(gbase + (size_t)nb * 2304);
        r0 = s[0]; r1 = s[1];
    };
    auto storel = [&]() {
        float* dst = isk ? &kl[sr][cc] : &vl[sr][cc];
        const unsigned short* u0 = (const unsigned short*)&r0;
        const unsigned short* u1 = (const unsigned short*)&r1;
        #pragma unroll
        for (int i = 0; i < 8; i++) dst[i] = bf2f(u0[i]);
        #pragma unroll
        for (int i = 0; i < 8; i++) dst[8 + i] = bf2f(u1[i]);
    };

    loadg(0);
    for (int c = 0; c < 16; c++) {
        storel();                       // chunk c regs -> LDS
        __syncthreads();                // writes visible
        if (c < 15) loadg((c + 1) * 32);   // prefetch next (hides under compute)
        #pragma unroll 8
        for (int r2 = 0; r2 < 32; r2++) {
            float kd = kl[r2][d];
            ks += kd;
            const float4* vv = (const float4*)&vl[r2][g * 16];
            float4 a0 = vv[0], a1 = vv[1], a2 = vv[2], a3 = vv[3];
            kv[0]  += kd * a0.x; kv[1]  += kd * a0.y; kv[2]  += kd * a0.z; kv[3]  += kd * a0.w;
            kv[4]  += kd * a1.x; kv[5]  += kd * a1.y; kv[6]  += kd * a1.z; kv[7]  += kd * a1.w;
            kv[8]  += kd * a2.x; kv[9]  += kd * a2.y; kv[10] += kd * a2.z; kv[11] += kd * a2.w;
            kv[12] += kd * a3.x; kv[13] += kd * a3.y; kv[14] += kd * a3.z; kv[15] += kd * a3.w;
        }
        __syncthreads();                // all reads done before next storel
    }
    float* dstg = kvbuf + (size_t)bh * 4160;
    #pragma unroll
    for (int j = 0; j < 16; j++)
        atomicAdd(&dstg[(g * 16 + j) * 64 + d], kv[j]);   // transposed: [e][d]
    if (g == 0) atomicAdd(&dstg[4096 + d], ks);
}

// ---------------- linear attention: apply via MFMA -------------------------
__global__ __launch_bounds__(256) void attn_apply(
    const unsigned short* __restrict__ qkv, const float* __restrict__ kvbuf,
    unsigned short* __restrict__ attnC)
{
    int blk = blockIdx.x;
    int nchunk = blk & 31;
    int bh = blk >> 5;
    int b = bh / 12, h = bh % 12;
    int n0 = nchunk * 128;
    int t = threadIdx.x;
    int lane = t & 63, wave = t >> 6;
    __shared__ __align__(16) unsigned short ql[128][72];
    __shared__ __align__(16) unsigned short Bs[80][72];

    {   // stage kvT (fp32->bf16) rows 0..63; ksum row 64; zeros 65..79
        const float* kvg = kvbuf + (size_t)bh * 4160;
        int e = t >> 2, d0 = (t & 3) * 16;
        const float4* src4 = (const float4*)(kvg + e * 64 + d0);
        #pragma unroll
        for (int i = 0; i < 4; i++) {
            float4 v = src4[i];
            unsigned long long pk = (unsigned long long)f2bf(v.x)
                | ((unsigned long long)f2bf(v.y) << 16)
                | ((unsigned long long)f2bf(v.z) << 32)
                | ((unsigned long long)f2bf(v.w) << 48);
            *(unsigned long long*)&Bs[e][d0 + i * 4] = pk;
        }
        if (t < 64) {
            Bs[64][t] = f2bf(kvg[4096 + t]);
            #pragma unroll
            for (int r = 65; r < 80; r++) Bs[r][t] = 0;
        }
    }
    {   // stage q rows (raw bf16 copy)
        int r = t >> 1, c0 = (t & 1) * 32;
        const uint4* src = (const uint4*)(qkv + (size_t)(b * 4096 + n0 + r) * 2304 + h * 64 + c0);
        uint4* dst = (uint4*)&ql[r][c0];
        #pragma unroll
        for (int i = 0; i < 4; i++) dst[i] = src[i];
    }
    __syncthreads();

    int frow = lane & 15, quad = lane >> 4;
    floatx4 acc[2][5];
    #pragma unroll
    for (int it = 0; it < 2; it++)
        #pragma unroll
        for (int jt = 0; jt < 5; jt++)
            acc[it][jt] = (floatx4){0.f, 0.f, 0.f, 0.f};

    #pragma unroll
    for (int ks = 0; ks < 2; ks++) {
        int fk = ks * 32 + quad * 8;
        short8 a0 = *(const short8*)&ql[wave * 32 + frow][fk];
        short8 a1 = *(const short8*)&ql[wave * 32 + 16 + frow][fk];
        #pragma unroll
        for (int jt = 0; jt < 5; jt++) {
            short8 bb = *(const short8*)&Bs[jt * 16 + frow][fk];
            acc[0][jt] = __builtin_amdgcn_mfma_f32_16x16x32_bf16(a0, bb, acc[0][jt], 0, 0, 0);
            acc[1][jt] = __builtin_amdgcn_mfma_f32_16x16x32_bf16(a1, bb, acc[1][jt], 0, 0, 0);
        }
    }

    #pragma unroll
    for (int it = 0; it < 2; it++) {
        #pragma unroll
        for (int rr = 0; rr < 4; rr++) {
            float nv = __shfl(acc[it][4][rr], (lane & 48));   // norm from col 0 of tile 4
            float inv = 1.0f / (nv + 1e-6f);
            int row = n0 + wave * 32 + it * 16 + quad * 4 + rr;
            size_t obase = (size_t)(b * 4096 + row) * 768 + h * 64;
            #pragma unroll
            for (int jt = 0; jt < 4; jt++)
                attnC[obase + jt * 16 + frow] = f2bf(acc[it][jt][rr] * inv);
        }
    }
}

// ---------------------------------------------------------------------------
extern "C" void kernel_launch(void* const* d_in, const int* in_sizes, int n_in,
                              void* d_out, int out_size, void* d_ws, size_t ws_size,
                              hipStream_t stream)
{
    const float* x      = (const float*)d_in[0];
    const float* w_qkv  = (const float*)d_in[1];
    const float* b_qkv  = (const float*)d_in[2];
    const float* w_proj = (const float*)d_in[3];
    const float* b_proj = (const float*)d_in[4];
    const float* g1     = (const float*)d_in[5];
    const float* be1    = (const float*)d_in[6];
    const float* g2     = (const float*)d_in[7];
    const float* be2    = (const float*)d_in[8];
    const float* w_down = (const float*)d_in[9];
    const float* b_down = (const float*)d_in[10];
    const float* w_up   = (const float*)d_in[11];
    const float* b_up   = (const float*)d_in[12];
    const float* g3     = (const float*)d_in[13];
    const float* be3    = (const float*)d_in[14];

    char* p = (char*)d_ws;
    auto take = [&](size_t b) { char* q = p; p += (b + 255) & ~(size_t)255; return q; };
    unsigned short* wtq  = (unsigned short*)take((size_t)2304 * 768 * 2);
    unsigned short* wtp  = (unsigned short*)take((size_t)768 * 768 * 2);
    unsigned short* wtd  = (unsigned short*)take((size_t)384 * 768 * 2);
    unsigned short* wtu  = (unsigned short*)take((size_t)768 * 384 * 2);
    unsigned short* bufA = (unsigned short*)take((size_t)32768 * 768 * 2);  // ln1 / attnC
    unsigned short* qkvb = (unsigned short*)take((size_t)32768 * 2304 * 2); // qkv; then r/projout/upout
    float*          kvb  = (float*)take((size_t)96 * 4160 * 4);
    unsigned short* hbuf = (unsigned short*)take((size_t)32768 * 384 * 2);
    // qkv dead after attn_apply; carve its 151 MB into three 50 MB bf16 buffers
    unsigned short* rbuf    = qkvb;
    unsigned short* projout = qkvb + (size_t)32768 * 768;
    unsigned short* upout   = qkvb + (size_t)2 * 32768 * 768;

    size_t needed = (size_t)(p - (char*)d_ws);
    if (needed > ws_size)
        fprintf(stderr, "WARNING: ws too small: need %zu have %zu\n", needed, ws_size);

    transpose_all<<<2880, 256, 0, stream>>>(w_qkv, w_proj, w_down, w_up, wtq, wtp, wtd, wtu);
    hipMemsetAsync(kvb, 0, (size_t)96 * 4160 * 4, stream);

    // ln1 = LN(x) (bf16)
    ln_kernel<true><<<16384, 384, 0, stream>>>(x, g1, be1, bufA);
    // qkv = ln1 @ Wqkv + b, elu+1 on q,k   (grid: col-fastest, round-0 mapping)
    gemm_kernel<0><<<dim3(18, 256), 256, 0, stream>>>(bufA, wtq, b_qkv, qkvb, 32768, 768, 2304);
    // attention
    kv_accum<<<768, 256, 0, stream>>>(qkvb, kvb);
    attn_apply<<<3072, 256, 0, stream>>>(qkvb, kvb, bufA);
    // projout = attn @ Wproj + b (bf16, no residual)
    gemm_kernel<1><<<dim3(6, 256), 256, 0, stream>>>(bufA, wtp, b_proj, projout, 32768, 768, 768);
    // r = LN(x + projout) (bf16)
    add_ln_kernel<true, false><<<16384, 384, 0, stream>>>(projout, x, g2, be2, rbuf);
    // h = gelu(r @ Wdown + b) (bf16)
    gemm_kernel<2><<<dim3(3, 256), 256, 0, stream>>>(rbuf, wtd, b_down, hbuf, 32768, 768, 384);
    // upout = h @ Wup + b (bf16)
    gemm_kernel<1><<<dim3(6, 256), 256, 0, stream>>>(hbuf, wtu, b_up, upout, 32768, 384, 768);
    // out = LN(r + upout) (fp32, d_out)
    add_ln_kernel<false, true><<<16384, 384, 0, stream>>>(upout, rbuf, g3, be3, (float*)d_out);
}

// Round 7
// 611.944 us; speedup vs baseline: 1.1670x; 1.0566x over previous
//
#include <hip/hip_runtime.h>
#include <hip/hip_bf16.h>
#include <cstdio>

// ---------------------------------------------------------------------------
// DinomalyBlock forward: B=8, N=4096, C=768, H=12, D=64, BN=384
// ---------------------------------------------------------------------------

typedef __attribute__((ext_vector_type(8))) short short8;
typedef __attribute__((ext_vector_type(4))) float floatx4;

__device__ __forceinline__ float bf2f(unsigned short u) {
    return __uint_as_float(((unsigned int)u) << 16);
}
__device__ __forceinline__ unsigned short f2bf(float f) {
    __hip_bfloat16 h = __float2bfloat16(f);
    return *reinterpret_cast<unsigned short*>(&h);
}

// async global->LDS, 16B/lane; LDS dest = wave-uniform base + lane*16
__device__ __forceinline__ void async_copy16(const unsigned short* g, unsigned short* l) {
    __builtin_amdgcn_global_load_lds(
        (const __attribute__((address_space(1))) unsigned int*)g,
        (__attribute__((address_space(3))) unsigned int*)l, 16, 0, 0);
}

__device__ __forceinline__ floatx4 MFMA16(short8 a, short8 b, floatx4 c) {
    return __builtin_amdgcn_mfma_f32_16x16x32_bf16(a, b, c, 0, 0, 0);
}

// ---------------- all weight transposes in one launch ----------------------
// W: [K][Nc] fp32 -> Wt: [Nc][K] bf16, 32x32 tiles
__global__ __launch_bounds__(256) void transpose_all(
    const float* __restrict__ wq, const float* __restrict__ wp,
    const float* __restrict__ wd, const float* __restrict__ wu,
    unsigned short* __restrict__ tq, unsigned short* __restrict__ tp,
    unsigned short* __restrict__ td, unsigned short* __restrict__ tu)
{
    int blk = blockIdx.x;
    const float* w; unsigned short* o; int K, Nc, tx32;
    if (blk < 1728)      { w = wq; o = tq; K = 768; Nc = 2304; tx32 = 24; }
    else if (blk < 2304) { w = wp; o = tp; K = 768; Nc = 768;  tx32 = 24; blk -= 1728; }
    else if (blk < 2592) { w = wd; o = td; K = 768; Nc = 384;  tx32 = 24; blk -= 2304; }
    else                 { w = wu; o = tu; K = 384; Nc = 768;  tx32 = 12; blk -= 2592; }
    int kb = (blk % tx32) * 32, nb = (blk / tx32) * 32;
    __shared__ float tile[32][33];
    int tx = threadIdx.x & 31, ty = threadIdx.x >> 5;   // 32x8
    #pragma unroll
    for (int i = 0; i < 32; i += 8)
        tile[ty + i][tx] = w[(size_t)(kb + ty + i) * Nc + nb + tx];
    __syncthreads();
    #pragma unroll
    for (int i = 0; i < 32; i += 8)
        o[(size_t)(nb + ty + i) * K + kb + tx] = f2bf(tile[tx][ty + i]);
}

// ---------------- LayerNorm over C=768: one row per wave -------------------
// 256 thr = 4 rows/block; lane owns 12 elems; pure shfl_xor butterfly,
// no barriers, no LDS.
template<bool OBF16>
__global__ __launch_bounds__(256) void ln_kernel(
    const float* __restrict__ in, const float* __restrict__ gw,
    const float* __restrict__ bw, void* __restrict__ outp)
{
    int t = threadIdx.x;
    int lane = t & 63, wave = t >> 6;
    int row = blockIdx.x * 4 + wave;
    const float4* src = (const float4*)(in + (size_t)row * 768);
    float4 x0 = src[lane], x1 = src[lane + 64], x2 = src[lane + 128];
    float s  = (x0.x + x0.y + x0.z + x0.w)
             + (x1.x + x1.y + x1.z + x1.w)
             + (x2.x + x2.y + x2.z + x2.w);
    float ss = (x0.x * x0.x + x0.y * x0.y + x0.z * x0.z + x0.w * x0.w)
             + (x1.x * x1.x + x1.y * x1.y + x1.z * x1.z + x1.w * x1.w)
             + (x2.x * x2.x + x2.y * x2.y + x2.z * x2.z + x2.w * x2.w);
    #pragma unroll
    for (int o = 1; o < 64; o <<= 1) {
        s += __shfl_xor(s, o);
        ss += __shfl_xor(ss, o);
    }
    float mu = s * (1.0f / 768.0f);
    float var = ss * (1.0f / 768.0f) - mu * mu;
    float rstd = rsqrtf(var + 1e-5f);
    float4 g0 = ((const float4*)gw)[lane], g1 = ((const float4*)gw)[lane + 64],
           g2 = ((const float4*)gw)[lane + 128];
    float4 b0 = ((const float4*)bw)[lane], b1 = ((const float4*)bw)[lane + 64],
           b2 = ((const float4*)bw)[lane + 128];
    float4 y0, y1, y2;
    y0.x = (x0.x - mu) * rstd * g0.x + b0.x; y0.y = (x0.y - mu) * rstd * g0.y + b0.y;
    y0.z = (x0.z - mu) * rstd * g0.z + b0.z; y0.w = (x0.w - mu) * rstd * g0.w + b0.w;
    y1.x = (x1.x - mu) * rstd * g1.x + b1.x; y1.y = (x1.y - mu) * rstd * g1.y + b1.y;
    y1.z = (x1.z - mu) * rstd * g1.z + b1.z; y1.w = (x1.w - mu) * rstd * g1.w + b1.w;
    y2.x = (x2.x - mu) * rstd * g2.x + b2.x; y2.y = (x2.y - mu) * rstd * g2.y + b2.y;
    y2.z = (x2.z - mu) * rstd * g2.z + b2.z; y2.w = (x2.w - mu) * rstd * g2.w + b2.w;
    if (OBF16) {
        uint2* dst = (uint2*)outp + (size_t)row * 192;
        uint2 p0, p1, p2;
        p0.x = (unsigned int)f2bf(y0.x) | ((unsigned int)f2bf(y0.y) << 16);
        p0.y = (unsigned int)f2bf(y0.z) | ((unsigned int)f2bf(y0.w) << 16);
        p1.x = (unsigned int)f2bf(y1.x) | ((unsigned int)f2bf(y1.y) << 16);
        p1.y = (unsigned int)f2bf(y1.z) | ((unsigned int)f2bf(y1.w) << 16);
        p2.x = (unsigned int)f2bf(y2.x) | ((unsigned int)f2bf(y2.y) << 16);
        p2.y = (unsigned int)f2bf(y2.z) | ((unsigned int)f2bf(y2.w) << 16);
        dst[lane] = p0; dst[lane + 64] = p1; dst[lane + 128] = p2;
    } else {
        float4* dst = (float4*)outp + (size_t)row * 192;
        dst[lane] = y0; dst[lane + 64] = y1; dst[lane + 128] = y2;
    }
}

// ---------------- fused residual add + LayerNorm: one row per wave ---------
// s = bf16(y) + res ; out = LN(s).  No barriers, no LDS.
template<bool RES_F32, bool OUT_F32>
__global__ __launch_bounds__(256) void add_ln_kernel(
    const unsigned short* __restrict__ y, const void* __restrict__ resv,
    const float* __restrict__ gw, const float* __restrict__ bw,
    void* __restrict__ outp)
{
    int t = threadIdx.x;
    int lane = t & 63, wave = t >> 6;
    int row = blockIdx.x * 4 + wave;
    const uint2* ysrc = (const uint2*)(y + (size_t)row * 768);
    uint2 ya = ysrc[lane], yb = ysrc[lane + 64], yc = ysrc[lane + 128];
    float v[12];
    v[0] = bf2f((unsigned short)(ya.x & 0xffff)); v[1] = bf2f((unsigned short)(ya.x >> 16));
    v[2] = bf2f((unsigned short)(ya.y & 0xffff)); v[3] = bf2f((unsigned short)(ya.y >> 16));
    v[4] = bf2f((unsigned short)(yb.x & 0xffff)); v[5] = bf2f((unsigned short)(yb.x >> 16));
    v[6] = bf2f((unsigned short)(yb.y & 0xffff)); v[7] = bf2f((unsigned short)(yb.y >> 16));
    v[8] = bf2f((unsigned short)(yc.x & 0xffff)); v[9] = bf2f((unsigned short)(yc.x >> 16));
    v[10] = bf2f((unsigned short)(yc.y & 0xffff)); v[11] = bf2f((unsigned short)(yc.y >> 16));
    if (RES_F32) {
        const float4* rsrc = (const float4*)((const float*)resv + (size_t)row * 768);
        float4 r0 = rsrc[lane], r1 = rsrc[lane + 64], r2 = rsrc[lane + 128];
        v[0] += r0.x; v[1] += r0.y; v[2] += r0.z; v[3] += r0.w;
        v[4] += r1.x; v[5] += r1.y; v[6] += r1.z; v[7] += r1.w;
        v[8] += r2.x; v[9] += r2.y; v[10] += r2.z; v[11] += r2.w;
    } else {
        const uint2* rsrc = (const uint2*)((const unsigned short*)resv + (size_t)row * 768);
        uint2 r0 = rsrc[lane], r1 = rsrc[lane + 64], r2 = rsrc[lane + 128];
        v[0] += bf2f((unsigned short)(r0.x & 0xffff)); v[1] += bf2f((unsigned short)(r0.x >> 16));
        v[2] += bf2f((unsigned short)(r0.y & 0xffff)); v[3] += bf2f((unsigned short)(r0.y >> 16));
        v[4] += bf2f((unsigned short)(r1.x & 0xffff)); v[5] += bf2f((unsigned short)(r1.x >> 16));
        v[6] += bf2f((unsigned short)(r1.y & 0xffff)); v[7] += bf2f((unsigned short)(r1.y >> 16));
        v[8] += bf2f((unsigned short)(r2.x & 0xffff)); v[9] += bf2f((unsigned short)(r2.x >> 16));
        v[10] += bf2f((unsigned short)(r2.y & 0xffff)); v[11] += bf2f((unsigned short)(r2.y >> 16));
    }
    float s = 0.f, ss = 0.f;
    #pragma unroll
    for (int i = 0; i < 12; i++) { s += v[i]; ss += v[i] * v[i]; }
    #pragma unroll
    for (int o = 1; o < 64; o <<= 1) {
        s += __shfl_xor(s, o);
        ss += __shfl_xor(ss, o);
    }
    float mu = s * (1.0f / 768.0f);
    float var = ss * (1.0f / 768.0f) - mu * mu;
    float rstd = rsqrtf(var + 1e-5f);
    float4 g0 = ((const float4*)gw)[lane], g1 = ((const float4*)gw)[lane + 64],
           g2 = ((const float4*)gw)[lane + 128];
    float4 b0 = ((const float4*)bw)[lane], b1 = ((const float4*)bw)[lane + 64],
           b2 = ((const float4*)bw)[lane + 128];
    float yv[12];
    yv[0] = (v[0] - mu) * rstd * g0.x + b0.x; yv[1] = (v[1] - mu) * rstd * g0.y + b0.y;
    yv[2] = (v[2] - mu) * rstd * g0.z + b0.z; yv[3] = (v[3] - mu) * rstd * g0.w + b0.w;
    yv[4] = (v[4] - mu) * rstd * g1.x + b1.x; yv[5] = (v[5] - mu) * rstd * g1.y + b1.y;
    yv[6] = (v[6] - mu) * rstd * g1.z + b1.z; yv[7] = (v[7] - mu) * rstd * g1.w + b1.w;
    yv[8] = (v[8] - mu) * rstd * g2.x + b2.x; yv[9] = (v[9] - mu) * rstd * g2.y + b2.y;
    yv[10] = (v[10] - mu) * rstd * g2.z + b2.z; yv[11] = (v[11] - mu) * rstd * g2.w + b2.w;
    if (OUT_F32) {
        float4* dst = (float4*)outp + (size_t)row * 192;
        dst[lane] = make_float4(yv[0], yv[1], yv[2], yv[3]);
        dst[lane + 64] = make_float4(yv[4], yv[5], yv[6], yv[7]);
        dst[lane + 128] = make_float4(yv[8], yv[9], yv[10], yv[11]);
    } else {
        uint2* dst = (uint2*)outp + (size_t)row * 192;
        uint2 p0, p1, p2;
        p0.x = (unsigned int)f2bf(yv[0]) | ((unsigned int)f2bf(yv[1]) << 16);
        p0.y = (unsigned int)f2bf(yv[2]) | ((unsigned int)f2bf(yv[3]) << 16);
        p1.x = (unsigned int)f2bf(yv[4]) | ((unsigned int)f2bf(yv[5]) << 16);
        p1.y = (unsigned int)f2bf(yv[6]) | ((unsigned int)f2bf(yv[7]) << 16);
        p2.x = (unsigned int)f2bf(yv[8]) | ((unsigned int)f2bf(yv[9]) << 16);
        p2.y = (unsigned int)f2bf(yv[10]) | ((unsigned int)f2bf(yv[11]) << 16);
        dst[lane] = p0; dst[lane + 64] = p1; dst[lane + 128] = p2;
    }
}

// ---------------- MFMA GEMM: out = A[M,K](bf16) @ Wt[Nc,K]^T + bias --------
// BK=64, XOR-swizzled LDS; grid = dim3(NCT, NRT): col-fastest dispatch so
// consecutive blocks share one A row-panel (round-0 proven mapping).
// MODE 0: elu+1 on cols<1536 (qkv) | 1: plain | 2: exact GELU
template<int MODE>
__global__ __launch_bounds__(256, 4) void gemm_kernel(
    const unsigned short* __restrict__ A,
    const unsigned short* __restrict__ Wt,
    const float* __restrict__ bias,
    unsigned short* __restrict__ outp,
    int M, int K, int Nc)
{
    __shared__ __align__(16) unsigned short As[128][64];
    __shared__ __align__(16) unsigned short Bs[128][64];
    const int row0 = blockIdx.y * 128;   // slow dim
    const int col0 = blockIdx.x * 128;   // fast dim -> col-fastest dispatch
    const int t = threadIdx.x;
    const int lane = t & 63;
    const int wave = t >> 6;
    const int wm = (wave >> 1) * 64;
    const int wn = (wave & 1) * 64;
    const int frow = lane & 15;
    const int quad = lane >> 4;
    const int lrow = lane >> 3;                 // 0..7 within staging group
    const int lchunk = (lane & 7) ^ lrow;       // logical chunk this lane fetches

    floatx4 acc[4][4];
    #pragma unroll
    for (int i = 0; i < 4; i++)
        #pragma unroll
        for (int j = 0; j < 4; j++)
            acc[i][j] = (floatx4){0.f, 0.f, 0.f, 0.f};

    for (int k0 = 0; k0 < K; k0 += 64) {
        __syncthreads();   // previous iter's frag reads done
        #pragma unroll
        for (int q = 0; q < 4; q++) {
            int r = wave * 32 + q * 8 + lrow;
            async_copy16(A  + (size_t)(row0 + r) * K + k0 + lchunk * 8, &As[wave * 32 + q * 8][0]);
            async_copy16(Wt + (size_t)(col0 + r) * K + k0 + lchunk * 8, &Bs[wave * 32 + q * 8][0]);
        }
        __syncthreads();   // drains vmcnt
        #pragma unroll
        for (int ks = 0; ks < 2; ks++) {
            const int pc = ((ks * 4 + quad) ^ (frow & 7)) * 8;
            short8 af[4], bf4[4];
            #pragma unroll
            for (int i = 0; i < 4; i++) af[i] = *(const short8*)&As[wm + i * 16 + frow][pc];
            #pragma unroll
            for (int j = 0; j < 4; j++) bf4[j] = *(const short8*)&Bs[wn + j * 16 + frow][pc];
            #pragma unroll
            for (int i = 0; i < 4; i++)
                #pragma unroll
                for (int j = 0; j < 4; j++)
                    acc[i][j] = MFMA16(af[i], bf4[j], acc[i][j]);
        }
    }

    #pragma unroll
    for (int i = 0; i < 4; i++) {
        #pragma unroll
        for (int j = 0; j < 4; j++) {
            int col = col0 + wn + j * 16 + frow;
            float bcol = bias[col];
            #pragma unroll
            for (int rr = 0; rr < 4; rr++) {
                int row = row0 + wm + i * 16 + quad * 4 + rr;
                float v = acc[i][j][rr] + bcol;
                if (MODE == 0) {
                    if (col < 1536) v = (v > 0.f) ? (v + 1.f) : expf(v);
                } else if (MODE == 2) {
                    v = 0.5f * v * (1.0f + erff(v * 0.70710678118654752f));
                }
                outp[(size_t)row * Nc + col] = f2bf(v);
            }
        }
    }
}

// ---------------- linear attention: kv accumulation ------------------------
// grid = B*H*8 (512 rows each); kvbuf[bh] 4160 fp32: [e*64+d]=kvT, [4096+d]=ksum
// Single-buffer LDS (35 KB) -> 4 blocks/CU; next chunk register-prefetched
// so HBM latency hides under compute. Accumulation order unchanged.
__global__ __launch_bounds__(256, 4) void kv_accum(
    const unsigned short* __restrict__ qkv, float* __restrict__ kvbuf)
{
    int blk = blockIdx.x;
    int chunk = blk & 7;
    int bh = blk >> 3;
    int b = bh / 12, h = bh % 12;
    int n0 = chunk * 512;
    int t = threadIdx.x;
    int d = t & 63, g = t >> 6;
    __shared__ float kl[32][68];
    __shared__ float vl[32][68];
    float kv[16];
    #pragma unroll
    for (int j = 0; j < 16; j++) kv[j] = 0.f;
    float ks = 0.f;

    int sr = t >> 3;            // staging row 0..31
    int c16 = (t & 7) * 16;     // 0..112
    bool isk = c16 < 64;
    int cc = isk ? c16 : c16 - 64;
    const unsigned short* gbase =
        qkv + (size_t)(b * 4096 + n0 + sr) * 2304 + (isk ? 768 : 1536) + h * 64 + cc;
    uint4 r0, r1;
    auto loadg = [&](int nb) {
        const uint4* s = (const uint4*)(gbase + (size_t)nb * 2304);
        r0 = s[0]; r1 = s[1];
    };
    auto storel = [&]() {
        float* dst = isk ? &kl[sr][cc] : &vl[sr][cc];
        const unsigned short* u0 = (const unsigned short*)&r0;
        const unsigned short* u1 = (const unsigned short*)&r1;
        #pragma unroll
        for (int i = 0; i < 8; i++) dst[i] = bf2f(u0[i]);
        #pragma unroll
        for (int i = 0; i < 8; i++) dst[8 + i] = bf2f(u1[i]);
    };

    loadg(0);
    for (int c = 0; c < 16; c++) {
        storel();                       // chunk c regs -> LDS
        __syncthreads();                // writes visible
        if (c < 15) loadg((c + 1) * 32);   // prefetch next (hides under compute)
        #pragma unroll 8
        for (int r2 = 0; r2 < 32; r2++) {
            float kd = kl[r2][d];
            ks += kd;
            const float4* vv = (const float4*)&vl[r2][g * 16];
            float4 a0 = vv[0], a1 = vv[1], a2 = vv[2], a3 = vv[3];
            kv[0]  += kd * a0.x; kv[1]  += kd * a0.y; kv[2]  += kd * a0.z; kv[3]  += kd * a0.w;
            kv[4]  += kd * a1.x; kv[5]  += kd * a1.y; kv[6]  += kd * a1.z; kv[7]  += kd * a1.w;
            kv[8]  += kd * a2.x; kv[9]  += kd * a2.y; kv[10] += kd * a2.z; kv[11] += kd * a2.w;
            kv[12] += kd * a3.x; kv[13] += kd * a3.y; kv[14] += kd * a3.z; kv[15] += kd * a3.w;
        }
        __syncthreads();                // all reads done before next storel
    }
    float* dstg = kvbuf + (size_t)bh * 4160;
    #pragma unroll
    for (int j = 0; j < 16; j++)
        atomicAdd(&dstg[(g * 16 + j) * 64 + d], kv[j]);   // transposed: [e][d]
    if (g == 0) atomicAdd(&dstg[4096 + d], ks);
}

// ---------------- linear attention: apply via MFMA -------------------------
__global__ __launch_bounds__(256) void attn_apply(
    const unsigned short* __restrict__ qkv, const float* __restrict__ kvbuf,
    unsigned short* __restrict__ attnC)
{
    int blk = blockIdx.x;
    int nchunk = blk & 31;
    int bh = blk >> 5;
    int b = bh / 12, h = bh % 12;
    int n0 = nchunk * 128;
    int t = threadIdx.x;
    int lane = t & 63, wave = t >> 6;
    __shared__ __align__(16) unsigned short ql[128][72];
    __shared__ __align__(16) unsigned short Bs[80][72];

    {   // stage kvT (fp32->bf16) rows 0..63; ksum row 64; zeros 65..79
        const float* kvg = kvbuf + (size_t)bh * 4160;
        int e = t >> 2, d0 = (t & 3) * 16;
        const float4* src4 = (const float4*)(kvg + e * 64 + d0);
        #pragma unroll
        for (int i = 0; i < 4; i++) {
            float4 v = src4[i];
            unsigned long long pk = (unsigned long long)f2bf(v.x)
                | ((unsigned long long)f2bf(v.y) << 16)
                | ((unsigned long long)f2bf(v.z) << 32)
                | ((unsigned long long)f2bf(v.w) << 48);
            *(unsigned long long*)&Bs[e][d0 + i * 4] = pk;
        }
        if (t < 64) {
            Bs[64][t] = f2bf(kvg[4096 + t]);
            #pragma unroll
            for (int r = 65; r < 80; r++) Bs[r][t] = 0;
        }
    }
    {   // stage q rows (raw bf16 copy)
        int r = t >> 1, c0 = (t & 1) * 32;
        const uint4* src = (const uint4*)(qkv + (size_t)(b * 4096 + n0 + r) * 2304 + h * 64 + c0);
        uint4* dst = (uint4*)&ql[r][c0];
        #pragma unroll
        for (int i = 0; i < 4; i++) dst[i] = src[i];
    }
    __syncthreads();

    int frow = lane & 15, quad = lane >> 4;
    floatx4 acc[2][5];
    #pragma unroll
    for (int it = 0; it < 2; it++)
        #pragma unroll
        for (int jt = 0; jt < 5; jt++)
            acc[it][jt] = (floatx4){0.f, 0.f, 0.f, 0.f};

    #pragma unroll
    for (int ks = 0; ks < 2; ks++) {
        int fk = ks * 32 + quad * 8;
        short8 a0 = *(const short8*)&ql[wave * 32 + frow][fk];
        short8 a1 = *(const short8*)&ql[wave * 32 + 16 + frow][fk];
        #pragma unroll
        for (int jt = 0; jt < 5; jt++) {
            short8 bb = *(const short8*)&Bs[jt * 16 + frow][fk];
            acc[0][jt] = __builtin_amdgcn_mfma_f32_16x16x32_bf16(a0, bb, acc[0][jt], 0, 0, 0);
            acc[1][jt] = __builtin_amdgcn_mfma_f32_16x16x32_bf16(a1, bb, acc[1][jt], 0, 0, 0);
        }
    }

    // normalize and stage results into this wave's own (now dead) ql rows,
    // then rewrite coalesced: per store instr 8 rows x 128 B contiguous.
    #pragma unroll
    for (int it = 0; it < 2; it++) {
        #pragma unroll
        for (int rr = 0; rr < 4; rr++) {
            float nv = __shfl(acc[it][4][rr], (lane & 48));   // norm from col 0 of tile 4
            float inv = 1.0f / (nv + 1e-6f);
            int lr = it * 16 + quad * 4 + rr;                 // 0..31 local row
            #pragma unroll
            for (int jt = 0; jt < 4; jt++)
                ql[wave * 32 + lr][jt * 16 + frow] = f2bf(acc[it][jt][rr] * inv);
        }
    }
    // wave-private region: no barrier needed (same-wave LDS ordering)
    #pragma unroll
    for (int j = 0; j < 4; j++) {
        int u = j * 64 + lane;          // uint4 index in wave's 32x64 region
        int lr = u >> 3;                // row 0..31
        int c8 = (u & 7) * 8;           // elem col 0..56
        uint4 val = *(const uint4*)&ql[wave * 32 + lr][c8];
        int row = n0 + wave * 32 + lr;
        *(uint4*)&attnC[(size_t)(b * 4096 + row) * 768 + h * 64 + c8] = val;
    }
}

// ---------------------------------------------------------------------------
extern "C" void kernel_launch(void* const* d_in, const int* in_sizes, int n_in,
                              void* d_out, int out_size, void* d_ws, size_t ws_size,
                              hipStream_t stream)
{
    const float* x      = (const float*)d_in[0];
    const float* w_qkv  = (const float*)d_in[1];
    const float* b_qkv  = (const float*)d_in[2];
    const float* w_proj = (const float*)d_in[3];
    const float* b_proj = (const float*)d_in[4];
    const float* g1     = (const float*)d_in[5];
    const float* be1    = (const float*)d_in[6];
    const float* g2     = (const float*)d_in[7];
    const float* be2    = (const float*)d_in[8];
    const float* w_down = (const float*)d_in[9];
    const float* b_down = (const float*)d_in[10];
    const float* w_up   = (const float*)d_in[11];
    const float* b_up   = (const float*)d_in[12];
    const float* g3     = (const float*)d_in[13];
    const float* be3    = (const float*)d_in[14];

    char* p = (char*)d_ws;
    auto take = [&](size_t b) { char* q = p; p += (b + 255) & ~(size_t)255; return q; };
    unsigned short* wtq  = (unsigned short*)take((size_t)2304 * 768 * 2);
    unsigned short* wtp  = (unsigned short*)take((size_t)768 * 768 * 2);
    unsigned short* wtd  = (unsigned short*)take((size_t)384 * 768 * 2);
    unsigned short* wtu  = (unsigned short*)take((size_t)768 * 384 * 2);
    unsigned short* bufA = (unsigned short*)take((size_t)32768 * 768 * 2);  // ln1 / attnC
    unsigned short* qkvb = (unsigned short*)take((size_t)32768 * 2304 * 2); // qkv; then r/projout/upout
    float*          kvb  = (float*)take((size_t)96 * 4160 * 4);
    unsigned short* hbuf = (unsigned short*)take((size_t)32768 * 384 * 2);
    // qkv dead after attn_apply; carve its 151 MB into three 50 MB bf16 buffers
    unsigned short* rbuf    = qkvb;
    unsigned short* projout = qkvb + (size_t)32768 * 768;
    unsigned short* upout   = qkvb + (size_t)2 * 32768 * 768;

    size_t needed = (size_t)(p - (char*)d_ws);
    if (needed > ws_size)
        fprintf(stderr, "WARNING: ws too small: need %zu have %zu\n", needed, ws_size);

    transpose_all<<<2880, 256, 0, stream>>>(w_qkv, w_proj, w_down, w_up, wtq, wtp, wtd, wtu);
    hipMemsetAsync(kvb, 0, (size_t)96 * 4160 * 4, stream);

    // ln1 = LN(x) (bf16)
    ln_kernel<true><<<8192, 256, 0, stream>>>(x, g1, be1, bufA);
    // qkv = ln1 @ Wqkv + b, elu+1 on q,k   (grid: col-fastest, round-0 mapping)
    gemm_kernel<0><<<dim3(18, 256), 256, 0, stream>>>(bufA, wtq, b_qkv, qkvb, 32768, 768, 2304);
    // attention
    kv_accum<<<768, 256, 0, stream>>>(qkvb, kvb);
    attn_apply<<<3072, 256, 0, stream>>>(qkvb, kvb, bufA);
    // projout = attn @ Wproj + b (bf16, no residual)
    gemm_kernel<1><<<dim3(6, 256), 256, 0, stream>>>(bufA, wtp, b_proj, projout, 32768, 768, 768);
    // r = LN(x + projout) (bf16)
    add_ln_kernel<true, false><<<8192, 256, 0, stream>>>(projout, x, g2, be2, rbuf);
    // h = gelu(r @ Wdown + b) (bf16)
    gemm_kernel<2><<<dim3(3, 256), 256, 0, stream>>>(rbuf, wtd, b_down, hbuf, 32768, 768, 384);
    // upout = h @ Wup + b (bf16)
    gemm_kernel<1><<<dim3(6, 256), 256, 0, stream>>>(hbuf, wtu, b_up, upout, 32768, 384, 768);
    // out = LN(r + upout) (fp32, d_out)
    add_ln_kernel<false, true><<<8192, 256, 0, stream>>>(upout, rbuf, g3, be3, (float*)d_out);
}